// Round 2
// baseline (435.170 us; speedup 1.0000x reference)
//
#include <hip/hip_runtime.h>

#define DIM 256
#define NC 12

typedef __attribute__((ext_vector_type(8))) short short8;
typedef __attribute__((ext_vector_type(4))) float f32x4;

__device__ __forceinline__ short f32bf(float f) {
    unsigned u = __builtin_bit_cast(unsigned, f);
    unsigned r = u + 0x7FFFu + ((u >> 16) & 1u);
    return (short)(r >> 16);
}

__device__ __forceinline__ void gld_lds16(const void* g, void* l) {
    __builtin_amdgcn_global_load_lds((const __attribute__((address_space(1))) unsigned int*)g,
                                     (__attribute__((address_space(3))) unsigned int*)l, 16, 0, 0);
}

template<int CTRL>
__device__ __forceinline__ unsigned dppmax(unsigned x) {
    unsigned y = (unsigned)__builtin_amdgcn_update_dpp(0, (int)x, CTRL, 0xF, 0xF, true);
    return x > y ? x : y;
}

// ---------------------------------------------------------------- prep ------
__global__ __launch_bounds__(256) void k_prep(const float* __restrict__ bank,
        const float* __restrict__ W1, const float* __restrict__ W2,
        short* __restrict__ bnbf, double* __restrict__ binv,
        short* __restrict__ w1bf, short* __restrict__ w2bf)
{
    __shared__ double part[4];
    __shared__ double s_inv;
    const int bid = blockIdx.x, t = threadIdx.x;
    if (bid < 1024) {
        const int row = bid;
        if (row < 1000) {
            float v = bank[(size_t)row * DIM + t];
            double ssq = (double)v * (double)v;
            for (int o = 32; o > 0; o >>= 1) ssq += __shfl_down(ssq, o);
            if ((t & 63) == 0) part[t >> 6] = ssq;
            __syncthreads();
            if (t == 0) {
                double s = part[0] + part[1] + part[2] + part[3];
                double n = sqrt(s); if (n < 1e-12) n = 1e-12;
                double inv = 1.0 / n;
                binv[row] = inv; s_inv = inv;
            }
            __syncthreads();
            const int pcol = (((t >> 3) ^ (row & 7)) << 3) | (t & 7);
            bnbf[(size_t)row * DIM + pcol] = f32bf((float)((double)v * s_inv));
        } else {
            bnbf[(size_t)row * DIM + t] = 0;
            if (t == 0) binv[row] = 0.0;
        }
    } else if (bid < 1536) {
        const int i = (bid - 1024) * 256 + t;
        w1bf[i] = f32bf(W1[i]);
    } else {
        const int i = (bid - 1536) * 256 + t;
        w2bf[i] = f32bf(W2[i]);
    }
}

// ---------------------------------------------------------------- sims ------
// 32 queries/block, 512 blocks/slice -> 2 blocks/CU so the per-chunk
// vmcnt(0)+barrier drains overlap across blocks (was 1 block/CU).
__global__ __launch_bounds__(256) void k_sims(const float* __restrict__ feat,
        const short* __restrict__ bnbf, short* __restrict__ sims, int qoff)
{
    __shared__ alignas(16) short Qs[32 * 264];
    __shared__ alignas(16) short Ab[64 * 256];
    const int t = threadIdx.x, lane = t & 63, w = t >> 6;
    const int n16 = lane & 15, q4 = lane >> 4;

    {
        const int r = t >> 3, p = t & 7;
        const float4* src = (const float4*)(feat + (size_t)(qoff + blockIdx.x * 32 + r) * DIM + p * 32);
        short* dst = Qs + r * 264 + p * 32;
        #pragma unroll
        for (int i = 0; i < 8; ++i) {
            float4 v = src[i];
            dst[i*4+0] = f32bf(v.x); dst[i*4+1] = f32bf(v.y);
            dst[i*4+2] = f32bf(v.z); dst[i*4+3] = f32bf(v.w);
        }
    }
    const char* gA = (const char*)bnbf;
    char* lA = (char*)Ab;
    #pragma unroll
    for (int i = 0; i < 8; ++i)
        gld_lds16(gA + i * 4096 + t * 16, lA + i * 4096 + (t >> 6) * 1024);
    __syncthreads();

    short8 bq[8][2];
    #pragma unroll
    for (int kc = 0; kc < 8; ++kc)
        #pragma unroll
        for (int nt = 0; nt < 2; ++nt)
            bq[kc][nt] = *(const short8*)(Qs + (nt * 16 + n16) * 264 + kc * 32 + q4 * 8);

    const int ml = w * 16 + n16;
    int aoff[8];
    #pragma unroll
    for (int kc = 0; kc < 8; ++kc)
        aoff[kc] = (ml * 256 + (((kc * 4 + q4) ^ (ml & 7)) << 3)) * 2;

    const f32x4 vzero = {0.f, 0.f, 0.f, 0.f};
    for (int chunk = 0; chunk < 16; ++chunk) {
        f32x4 acc[2];
        acc[0] = vzero; acc[1] = vzero;
        #pragma unroll
        for (int kc = 0; kc < 8; ++kc) {
            short8 af = *(const short8*)(lA + aoff[kc]);
            #pragma unroll
            for (int nt = 0; nt < 2; ++nt)
                acc[nt] = __builtin_amdgcn_mfma_f32_16x16x32_bf16(af, bq[kc][nt], acc[nt], 0, 0, 0);
        }
        const int bankb = chunk * 64 + w * 16 + q4 * 4;
        #pragma unroll
        for (int nt = 0; nt < 2; ++nt) {
            const int qc = blockIdx.x * 32 + nt * 16 + n16;
            uint2 u;
            u.x = ((unsigned)(unsigned short)f32bf(acc[nt][0])) |
                  (((unsigned)(unsigned short)f32bf(acc[nt][1])) << 16);
            u.y = ((unsigned)(unsigned short)f32bf(acc[nt][2])) |
                  (((unsigned)(unsigned short)f32bf(acc[nt][3])) << 16);
            *(uint2*)(sims + (size_t)qc * 1024 + bankb) = u;
        }
        __syncthreads();
        if (chunk < 15) {
            #pragma unroll
            for (int i = 0; i < 8; ++i)
                gld_lds16(gA + (size_t)(chunk + 1) * 32768 + i * 4096 + t * 16,
                          lA + i * 4096 + (t >> 6) * 1024);
            __syncthreads();
        }
    }
}

// -------------------------------------------------------------- select ------
__global__ __launch_bounds__(256) void k_select(const short* __restrict__ sims,
        int* __restrict__ top, int qoff)
{
    const int t = threadIdx.x, lane = t & 63, w = t >> 6;
    const int q = blockIdx.x * 4 + w;
    const uint4* p = (const uint4*)(sims + (size_t)q * 1024 + lane * 16);
    uint4 a = p[0], b = p[1];

    unsigned k[16];
    {
        unsigned words[8] = {a.x, a.y, a.z, a.w, b.x, b.y, b.z, b.w};
        #pragma unroll
        for (int j = 0; j < 16; ++j) {
            unsigned h = (j & 1) ? (words[j >> 1] >> 16) : (words[j >> 1] & 0xFFFFu);
            unsigned m = (h ^ 0x8000u) ^ ((0u - (h >> 15)) & 0x7FFFu);
            int idx = lane * 16 + j;
            k[j] = (idx < 1000) ? ((m << 16) | (unsigned)idx) : 0u;
        }
    }
    #pragma unroll
    for (int sz = 2; sz <= 16; sz <<= 1)
        #pragma unroll
        for (int st = sz >> 1; st >= 1; st >>= 1)
            #pragma unroll
            for (int i = 0; i < 16; ++i) {
                int j = i ^ st;
                if (j > i) {
                    bool desc = ((i & sz) == 0);
                    unsigned lo = k[i], hi = k[j];
                    unsigned mx = lo > hi ? lo : hi;
                    unsigned mn = lo > hi ? hi : lo;
                    k[i] = desc ? mx : mn;
                    k[j] = desc ? mn : mx;
                }
            }
    unsigned mine = 0;
    #pragma unroll
    for (int r = 0; r < 12; ++r) {
        unsigned m = k[0];
        m = dppmax<0xB1>(m);
        m = dppmax<0x4E>(m);
        m = dppmax<0x141>(m);
        m = dppmax<0x140>(m);
        m = dppmax<0x142>(m);
        m = dppmax<0x143>(m);
        unsigned wm = (unsigned)__builtin_amdgcn_readlane((int)m, 63);
        if (lane == r) mine = wm;
        if (k[0] == wm) {
            #pragma unroll
            for (int s = 0; s < 12; ++s) k[s] = k[s + 1];
        }
    }
    if (lane < 12) top[(size_t)(qoff + q) * NC + lane] = (int)(mine & 0xFFFFu);
}

// -------------------------------------------------------------- refine ------
// Also emits featbf (bf16 copy of feat) so k_mlp can consume A-fragments
// straight from global with no LDS staging / no per-chunk barriers.
__global__ __launch_bounds__(256) void k_refine(const float* __restrict__ feat,
        const float* __restrict__ bank, const int* __restrict__ top,
        const double* __restrict__ binv, short* __restrict__ nf,
        short* __restrict__ featbf)
{
    __shared__ int    cidxL[16 * NC];
    __shared__ float  bdF[16 * NC];
    __shared__ double bdD[16 * NC];
    __shared__ float  simsF[16 * NC];
    __shared__ double simsD[16 * NC];
    __shared__ float  qiL[16];
    __shared__ int    flagL[16];
    __shared__ int    selidx[16][5];
    __shared__ float  selw[16][5];

    const int t = threadIdx.x, lane = t & 63, w = t >> 6;
    const int g = lane >> 4, u = lane & 15;
    const int ql = w * 4 + g;
    const int qbase = blockIdx.x * 16;
    const int q = qbase + ql;

    if (t < 16 * NC) {
        const int c = top[(size_t)qbase * NC + t];
        cidxL[t] = c;
        const double b = binv[c];
        bdD[t] = b; bdF[t] = (float)b;
    }
    __syncthreads();

    int ci[NC];
    #pragma unroll
    for (int c = 0; c < NC; ++c) ci[c] = cidxL[ql * NC + c];

    float qf[16];
    float ssf = 0.f;
    #pragma unroll
    for (int j = 0; j < 4; ++j) {
        float4 v = *(const float4*)(feat + (size_t)q * DIM + j * 64 + u * 4);
        qf[j*4+0] = v.x; qf[j*4+1] = v.y; qf[j*4+2] = v.z; qf[j*4+3] = v.w;
        ssf += v.x*v.x + v.y*v.y + v.z*v.z + v.w*v.w;
    }
    // emit bf16 feat copy (same f32bf rounding k_mlp used to apply inline)
    {
        short* fb = featbf + (size_t)q * DIM + u * 4;
        #pragma unroll
        for (int j = 0; j < 4; ++j) {
            uint2 pk;
            pk.x = ((unsigned)(unsigned short)f32bf(qf[j*4+0])) |
                   (((unsigned)(unsigned short)f32bf(qf[j*4+1])) << 16);
            pk.y = ((unsigned)(unsigned short)f32bf(qf[j*4+2])) |
                   (((unsigned)(unsigned short)f32bf(qf[j*4+3])) << 16);
            *(uint2*)(fb + j * 64) = pk;
        }
    }
    #pragma unroll
    for (int o = 1; o < 16; o <<= 1) ssf += __shfl_xor(ssf, o, 16);
    float nq = sqrtf(ssf); if (nq < 1e-12f) nq = 1e-12f;
    if (u == 0) qiL[ql] = 1.f / nq;

    float s[NC];
    #pragma unroll
    for (int c = 0; c < NC; ++c) {
        const float* brow = bank + (size_t)ci[c] * DIM + u * 4;
        float a0 = 0.f, a1 = 0.f, a2 = 0.f, a3 = 0.f;
        #pragma unroll
        for (int j = 0; j < 4; ++j) {
            float4 b = *(const float4*)(brow + j * 64);
            a0 += qf[j*4+0] * b.x; a1 += qf[j*4+1] * b.y;
            a2 += qf[j*4+2] * b.z; a3 += qf[j*4+3] * b.w;
        }
        s[c] = (a0 + a1) + (a2 + a3);
    }
    #pragma unroll
    for (int o = 1; o < 16; o <<= 1)
        #pragma unroll
        for (int c = 0; c < NC; ++c) s[c] += __shfl_xor(s[c], o, 16);
    #pragma unroll
    for (int c = 0; c < NC; ++c) if (u == c) simsF[ql * NC + c] = s[c];
    __syncthreads();

    if (t < 16) {
        const float qi2 = qiL[t];
        float vf[NC];
        unsigned long long key[NC];
        int cid[NC];
        #pragma unroll
        for (int c = 0; c < NC; ++c) {
            cid[c] = cidxL[t * NC + c];
            float v = simsF[t * NC + c] * qi2 * bdF[t * NC + c];
            vf[c] = v;
            unsigned ub = __builtin_bit_cast(unsigned, v);
            unsigned m = (ub >> 31) ? ~ub : (ub | 0x80000000u);
            key[c] = ((unsigned long long)m << 10) | (unsigned long long)(1023 - cid[c]);
        }
        int rank[NC];
        #pragma unroll
        for (int c = 0; c < NC; ++c) rank[c] = 0;
        #pragma unroll
        for (int c1 = 0; c1 < NC; ++c1)
            #pragma unroll
            for (int c2 = c1 + 1; c2 < NC; ++c2) {
                const bool gt = key[c1] > key[c2];
                rank[c2] += gt ? 1 : 0;
                rank[c1] += gt ? 0 : 1;
            }
        float v5 = 0.f, v6 = 0.f;
        #pragma unroll
        for (int c = 0; c < NC; ++c) {
            v5 += (rank[c] == 4) ? vf[c] : 0.f;
            v6 += (rank[c] == 5) ? vf[c] : 0.f;
        }
        flagL[t] = (v5 - v6) < 2e-6f;

        float vm = vf[0];
        #pragma unroll
        for (int c = 1; c < NC; ++c) vm = fmaxf(vm, vf[c]);
        float e[NC]; float wsum = 0.f;
        #pragma unroll
        for (int c = 0; c < NC; ++c) {
            float ex = __expf(vf[c] - vm);
            ex = (rank[c] < 5) ? ex : 0.f;
            e[c] = ex; wsum += ex;
        }
        const float inv = 1.f / wsum;
        #pragma unroll
        for (int k = 0; k < 5; ++k) {
            int idx = 0; float wv = 0.f;
            #pragma unroll
            for (int c = 0; c < NC; ++c) {
                const bool is = (rank[c] == k);
                idx += is ? cid[c] : 0;
                wv  += is ? e[c]  : 0.f;
            }
            selidx[t][k] = idx; selw[t][k] = wv * inv;
        }
    }
    __syncthreads();

    if (flagL[ql]) {
        double ssd = 0.0;
        #pragma unroll
        for (int j = 0; j < 16; ++j) ssd += (double)qf[j] * (double)qf[j];
        #pragma unroll
        for (int o = 1; o < 16; o <<= 1) ssd += __shfl_xor(ssd, o, 16);
        double nd = sqrt(ssd); if (nd < 1e-12) nd = 1e-12;
        const double qid = 1.0 / nd;
        double sd[NC];
        #pragma unroll
        for (int c = 0; c < NC; ++c) {
            const float* brow = bank + (size_t)ci[c] * DIM + u * 4;
            double a0 = 0, a1 = 0, a2 = 0, a3 = 0;
            #pragma unroll
            for (int j = 0; j < 4; ++j) {
                float4 b = *(const float4*)(brow + j * 64);
                a0 += (double)qf[j*4+0] * b.x; a1 += (double)qf[j*4+1] * b.y;
                a2 += (double)qf[j*4+2] * b.z; a3 += (double)qf[j*4+3] * b.w;
            }
            sd[c] = (a0 + a1) + (a2 + a3);
        }
        #pragma unroll
        for (int o = 1; o < 16; o <<= 1)
            #pragma unroll
            for (int c = 0; c < NC; ++c) sd[c] += __shfl_xor(sd[c], o, 16);
        #pragma unroll
        for (int c = 0; c < NC; ++c)
            if (u == c) simsD[ql * NC + c] = sd[c] * qid * bdD[ql * NC + c];
    }
    __syncthreads();

    if (t < 16 && flagL[t]) {
        double vd[NC];
        unsigned long long key[NC];
        int cid[NC];
        #pragma unroll
        for (int c = 0; c < NC; ++c) {
            cid[c] = cidxL[t * NC + c];
            double v = simsD[t * NC + c];
            vd[c] = v;
            unsigned long long ub = __builtin_bit_cast(unsigned long long, v);
            unsigned long long m = (ub >> 63) ? ~ub : (ub | 0x8000000000000000ULL);
            key[c] = (m & ~0x3FFULL) | (unsigned long long)(1023 - cid[c]);
        }
        int rank[NC];
        #pragma unroll
        for (int c = 0; c < NC; ++c) rank[c] = 0;
        #pragma unroll
        for (int c1 = 0; c1 < NC; ++c1)
            #pragma unroll
            for (int c2 = c1 + 1; c2 < NC; ++c2) {
                const bool gt = key[c1] > key[c2];
                rank[c2] += gt ? 1 : 0;
                rank[c1] += gt ? 0 : 1;
            }
        float vf[NC];
        #pragma unroll
        for (int c = 0; c < NC; ++c) vf[c] = (float)vd[c];
        float vm = vf[0];
        #pragma unroll
        for (int c = 1; c < NC; ++c) vm = fmaxf(vm, vf[c]);
        float e[NC]; float wsum = 0.f;
        #pragma unroll
        for (int c = 0; c < NC; ++c) {
            float ex = __expf(vf[c] - vm);
            ex = (rank[c] < 5) ? ex : 0.f;
            e[c] = ex; wsum += ex;
        }
        const float inv = 1.f / wsum;
        #pragma unroll
        for (int k = 0; k < 5; ++k) {
            int idx = 0; float wv = 0.f;
            #pragma unroll
            for (int c = 0; c < NC; ++c) {
                const bool is = (rank[c] == k);
                idx += is ? cid[c] : 0;
                wv  += is ? e[c]  : 0.f;
            }
            selidx[t][k] = idx; selw[t][k] = wv * inv;
        }
    }
    __syncthreads();

    float wk[5]; int ik[5];
    #pragma unroll
    for (int k = 0; k < 5; ++k) { wk[k] = selw[ql][k]; ik[k] = selidx[ql][k]; }
    float4 oa[4];
    #pragma unroll
    for (int j = 0; j < 4; ++j) { oa[j].x = 0.f; oa[j].y = 0.f; oa[j].z = 0.f; oa[j].w = 0.f; }
    #pragma unroll
    for (int k = 0; k < 5; ++k) {
        const float wc = wk[k];
        const float* brow = bank + (size_t)ik[k] * DIM + u * 4;
        #pragma unroll
        for (int j = 0; j < 4; ++j) {
            float4 b = *(const float4*)(brow + j * 64);
            oa[j].x += wc * b.x; oa[j].y += wc * b.y;
            oa[j].z += wc * b.z; oa[j].w += wc * b.w;
        }
    }
    short* od = nf + (size_t)q * DIM + u * 4;
    #pragma unroll
    for (int j = 0; j < 4; ++j) {
        uint2 pk;
        pk.x = ((unsigned)(unsigned short)f32bf(oa[j].x)) |
               (((unsigned)(unsigned short)f32bf(oa[j].y)) << 16);
        pk.y = ((unsigned)(unsigned short)f32bf(oa[j].z)) |
               (((unsigned)(unsigned short)f32bf(oa[j].w)) << 16);
        *(uint2*)(od + j * 64) = pk;
    }
}

// ---------------------------------------------------------- fused MLP v4 ----
// v3 was latency-bound at 37% occupancy: grid 1024 = 4 blocks/CU was the
// wave-parallelism cap. v4 halves the M-tile to 32 rows (grid 2048 = 8
// blocks/CU), acc[2][4] (32 regs), Hs 16.9 KB -> ~6 blocks/CU resident
// (launch_bounds min 6 waves/EU). Weights stream from L2 (2x refetch,
// ~0.8 GB over the dispatch = ~20 TB/s L2, under the 34.5 TB/s ceiling).
__global__ __launch_bounds__(256, 6) void k_mlp(const short* __restrict__ featbf,
        const short* __restrict__ nf, const short* __restrict__ w1bf,
        const short* __restrict__ w2bf, const float* __restrict__ b1,
        const float* __restrict__ b2, float* __restrict__ out)
{
    __shared__ alignas(16) short Hs[32 * 264];
    const int t = threadIdx.x, lane = t & 63, w = t >> 6;
    const int mb = blockIdx.x * 32;
    const int n16 = lane & 15, ko = (lane >> 4) << 3;
    const int rq = (lane >> 4) << 2, cc = lane & 15;
    const f32x4 vzero = {0.f, 0.f, 0.f, 0.f};

    f32x4 acc[2][4];
    #pragma unroll
    for (int a = 0; a < 2; ++a)
        #pragma unroll
        for (int b = 0; b < 4; ++b) acc[a][b] = vzero;

    const short* A0 = featbf + (size_t)mb * 256 + ko;
    const short* A1 = nf     + (size_t)mb * 256 + ko;
    const short* Wp = w1bf + (size_t)(w * 64 + n16) * 512 + ko;

    // ---- layer 1, K-chunks 0..7: A = featbf ----
    #pragma unroll
    for (int kc = 0; kc < 8; ++kc) {
        short8 af[2], bf[4];
        #pragma unroll
        for (int mt = 0; mt < 2; ++mt)
            af[mt] = *(const short8*)(A0 + (mt * 16 + n16) * 256 + kc * 32);
        #pragma unroll
        for (int nt = 0; nt < 4; ++nt)
            bf[nt] = *(const short8*)(Wp + (size_t)nt * 16 * 512 + kc * 32);
        #pragma unroll
        for (int mt = 0; mt < 2; ++mt)
            #pragma unroll
            for (int nt = 0; nt < 4; ++nt)
                acc[mt][nt] = __builtin_amdgcn_mfma_f32_16x16x32_bf16(af[mt], bf[nt], acc[mt][nt], 0, 0, 0);
    }
    // ---- layer 1, K-chunks 8..15: A = nf ----
    #pragma unroll
    for (int kc = 0; kc < 8; ++kc) {
        short8 af[2], bf[4];
        #pragma unroll
        for (int mt = 0; mt < 2; ++mt)
            af[mt] = *(const short8*)(A1 + (mt * 16 + n16) * 256 + kc * 32);
        #pragma unroll
        for (int nt = 0; nt < 4; ++nt)
            bf[nt] = *(const short8*)(Wp + (size_t)nt * 16 * 512 + (kc + 8) * 32);
        #pragma unroll
        for (int mt = 0; mt < 2; ++mt)
            #pragma unroll
            for (int nt = 0; nt < 4; ++nt)
                acc[mt][nt] = __builtin_amdgcn_mfma_f32_16x16x32_bf16(af[mt], bf[nt], acc[mt][nt], 0, 0, 0);
    }

    // epilogue 1: bias + relu -> Hs
    #pragma unroll
    for (int mt = 0; mt < 2; ++mt)
        #pragma unroll
        for (int nt = 0; nt < 4; ++nt) {
            const int row = mt * 16 + rq;
            const int col = w * 64 + nt * 16 + cc;
            const float bias = b1[col];
            #pragma unroll
            for (int rr = 0; rr < 4; ++rr) {
                float v = acc[mt][nt][rr] + bias;
                Hs[(row + rr) * 264 + col] = f32bf(fmaxf(v, 0.f));
            }
        }
    #pragma unroll
    for (int a = 0; a < 2; ++a)
        #pragma unroll
        for (int b = 0; b < 4; ++b) acc[a][b] = vzero;
    __syncthreads();

    // ---- layer 2: barrier-free K-loop (Hs read-only, weights global) ----
    #pragma unroll
    for (int kc = 0; kc < 8; ++kc) {
        short8 bf[4];
        #pragma unroll
        for (int nt = 0; nt < 4; ++nt)
            bf[nt] = *(const short8*)(w2bf + (size_t)(w * 64 + nt * 16 + n16) * 256 + kc * 32 + ko);
        short8 af[2];
        #pragma unroll
        for (int mt = 0; mt < 2; ++mt)
            af[mt] = *(const short8*)(Hs + (mt * 16 + n16) * 264 + kc * 32 + ko);
        #pragma unroll
        for (int mt = 0; mt < 2; ++mt)
            #pragma unroll
            for (int nt = 0; nt < 4; ++nt)
                acc[mt][nt] = __builtin_amdgcn_mfma_f32_16x16x32_bf16(af[mt], bf[nt], acc[mt][nt], 0, 0, 0);
    }
    #pragma unroll
    for (int mt = 0; mt < 2; ++mt)
        #pragma unroll
        for (int nt = 0; nt < 4; ++nt) {
            const int row = mb + mt * 16 + rq;
            const int col = w * 64 + nt * 16 + cc;
            const float bias = b2[col];
            #pragma unroll
            for (int rr = 0; rr < 4; ++rr)
                out[(size_t)(row + rr) * 256 + col] = acc[mt][nt][rr] + bias;
        }
}

// ------------------------------------------------------------- launcher -----
extern "C" void kernel_launch(void* const* d_in, const int* in_sizes, int n_in,
                              void* d_out, int out_size, void* d_ws, size_t ws_size,
                              hipStream_t stream) {
    const float* feat = (const float*)d_in[0];
    const float* bank = (const float*)d_in[1];
    const float* W1   = (const float*)d_in[2];
    const float* b1   = (const float*)d_in[3];
    const float* W2   = (const float*)d_in[4];
    const float* b2   = (const float*)d_in[5];
    float* out = (float*)d_out;

    char* ws = (char*)d_ws;
    short*  bnbf = (short*)(ws + 0);              // 1024*256*2   = 524288
    double* binv = (double*)(ws + 524288);        // 1024*8       = 8192
    short*  w1bf = (short*)(ws + 532480);         // 131072*2     = 262144
    short*  w2bf = (short*)(ws + 794624);         // 65536*2      = 131072
    int*    top  = (int*)(ws + 925696);           // 65536*12*4   = 3145728
    short*  nf   = (short*)(ws + 4071424);        // 65536*256*2  = 33554432
    short*  X    = (short*)(ws + 37625856);       // 33554432: sims slices
    // featbf ALIASES X: the sims/select slice loop is fully done before
    // k_refine runs, so the 33.5 MB slice buffer is dead by then.
    short*  featbf = X;                           // 65536*256*2  = 33554432
    // total 71180288 bytes

    k_prep<<<1792, 256, 0, stream>>>(bank, W1, W2, bnbf, binv, w1bf, w2bf);
    for (int s = 0; s < 4; ++s) {
        const int qoff = s * 16384;
        k_sims  <<<512,  256, 0, stream>>>(feat, bnbf, X, qoff);
        k_select<<<4096, 256, 0, stream>>>(X, top, qoff);
    }
    k_refine<<<4096, 256, 0, stream>>>(feat, bank, top, binv, nf, featbf);
    k_mlp   <<<2048, 256, 0, stream>>>(featbf, nf, w1bf, w2bf, b1, b2, out);
}

// Round 3
// 393.046 us; speedup vs baseline: 1.1072x; 1.1072x over previous
//
#include <hip/hip_runtime.h>

#define DIM 256
#define NC 12

typedef __attribute__((ext_vector_type(8))) short short8;
typedef __attribute__((ext_vector_type(4))) float f32x4;

__device__ __forceinline__ short f32bf(float f) {
    unsigned u = __builtin_bit_cast(unsigned, f);
    unsigned r = u + 0x7FFFu + ((u >> 16) & 1u);
    return (short)(r >> 16);
}

__device__ __forceinline__ void gld_lds16(const void* g, void* l) {
    __builtin_amdgcn_global_load_lds((const __attribute__((address_space(1))) unsigned int*)g,
                                     (__attribute__((address_space(3))) unsigned int*)l, 16, 0, 0);
}

template<int CTRL>
__device__ __forceinline__ unsigned dppmax(unsigned x) {
    unsigned y = (unsigned)__builtin_amdgcn_update_dpp(0, (int)x, CTRL, 0xF, 0xF, true);
    return x > y ? x : y;
}

// ---------------------------------------------------------------- prep ------
__global__ __launch_bounds__(256) void k_prep(const float* __restrict__ bank,
        const float* __restrict__ W1, const float* __restrict__ W2,
        short* __restrict__ bnbf, double* __restrict__ binv,
        short* __restrict__ w1bf, short* __restrict__ w2bf)
{
    __shared__ double part[4];
    __shared__ double s_inv;
    const int bid = blockIdx.x, t = threadIdx.x;
    if (bid < 1024) {
        const int row = bid;
        if (row < 1000) {
            float v = bank[(size_t)row * DIM + t];
            double ssq = (double)v * (double)v;
            for (int o = 32; o > 0; o >>= 1) ssq += __shfl_down(ssq, o);
            if ((t & 63) == 0) part[t >> 6] = ssq;
            __syncthreads();
            if (t == 0) {
                double s = part[0] + part[1] + part[2] + part[3];
                double n = sqrt(s); if (n < 1e-12) n = 1e-12;
                double inv = 1.0 / n;
                binv[row] = inv; s_inv = inv;
            }
            __syncthreads();
            const int pcol = (((t >> 3) ^ (row & 7)) << 3) | (t & 7);
            bnbf[(size_t)row * DIM + pcol] = f32bf((float)((double)v * s_inv));
        } else {
            bnbf[(size_t)row * DIM + t] = 0;
            if (t == 0) binv[row] = 0.0;
        }
    } else if (bid < 1536) {
        const int i = (bid - 1024) * 256 + t;
        w1bf[i] = f32bf(W1[i]);
    } else {
        const int i = (bid - 1536) * 256 + t;
        w2bf[i] = f32bf(W2[i]);
    }
}

// ------------------------------------------------------- sims + select ------
// 32 queries/block. After the MFMA chunk loop the block's 64 KB sims slice
// is L2-hot (just written, same XCD); the 4 waves immediately run the
// bitonic top-12 for their own 8 queries each, eliminating the separate
// k_select dispatches and the 134 MB HBM re-read of X.
__global__ __launch_bounds__(256) void k_sims(const float* __restrict__ feat,
        const short* __restrict__ bnbf, short* __restrict__ sims,
        int* __restrict__ top, int qoff)
{
    __shared__ alignas(16) short Qs[32 * 264];
    __shared__ alignas(16) short Ab[64 * 256];
    const int t = threadIdx.x, lane = t & 63, w = t >> 6;
    const int n16 = lane & 15, q4 = lane >> 4;

    {
        const int r = t >> 3, p = t & 7;
        const float4* src = (const float4*)(feat + (size_t)(qoff + blockIdx.x * 32 + r) * DIM + p * 32);
        short* dst = Qs + r * 264 + p * 32;
        #pragma unroll
        for (int i = 0; i < 8; ++i) {
            float4 v = src[i];
            dst[i*4+0] = f32bf(v.x); dst[i*4+1] = f32bf(v.y);
            dst[i*4+2] = f32bf(v.z); dst[i*4+3] = f32bf(v.w);
        }
    }
    const char* gA = (const char*)bnbf;
    char* lA = (char*)Ab;
    #pragma unroll
    for (int i = 0; i < 8; ++i)
        gld_lds16(gA + i * 4096 + t * 16, lA + i * 4096 + (t >> 6) * 1024);
    __syncthreads();

    short8 bq[8][2];
    #pragma unroll
    for (int kc = 0; kc < 8; ++kc)
        #pragma unroll
        for (int nt = 0; nt < 2; ++nt)
            bq[kc][nt] = *(const short8*)(Qs + (nt * 16 + n16) * 264 + kc * 32 + q4 * 8);

    const int ml = w * 16 + n16;
    int aoff[8];
    #pragma unroll
    for (int kc = 0; kc < 8; ++kc)
        aoff[kc] = (ml * 256 + (((kc * 4 + q4) ^ (ml & 7)) << 3)) * 2;

    const f32x4 vzero = {0.f, 0.f, 0.f, 0.f};
    for (int chunk = 0; chunk < 16; ++chunk) {
        f32x4 acc[2];
        acc[0] = vzero; acc[1] = vzero;
        #pragma unroll
        for (int kc = 0; kc < 8; ++kc) {
            short8 af = *(const short8*)(lA + aoff[kc]);
            #pragma unroll
            for (int nt = 0; nt < 2; ++nt)
                acc[nt] = __builtin_amdgcn_mfma_f32_16x16x32_bf16(af, bq[kc][nt], acc[nt], 0, 0, 0);
        }
        const int bankb = chunk * 64 + w * 16 + q4 * 4;
        #pragma unroll
        for (int nt = 0; nt < 2; ++nt) {
            const int qc = blockIdx.x * 32 + nt * 16 + n16;
            uint2 u;
            u.x = ((unsigned)(unsigned short)f32bf(acc[nt][0])) |
                  (((unsigned)(unsigned short)f32bf(acc[nt][1])) << 16);
            u.y = ((unsigned)(unsigned short)f32bf(acc[nt][2])) |
                  (((unsigned)(unsigned short)f32bf(acc[nt][3])) << 16);
            *(uint2*)(sims + (size_t)qc * 1024 + bankb) = u;
        }
        __syncthreads();
        if (chunk < 15) {
            #pragma unroll
            for (int i = 0; i < 8; ++i)
                gld_lds16(gA + (size_t)(chunk + 1) * 32768 + i * 4096 + t * 16,
                          lA + i * 4096 + (t >> 6) * 1024);
            __syncthreads();
        }
    }

    // ---- fused select: 4 waves x 8 queries each, reads are L2 hits ----
    for (int i = 0; i < 8; ++i) {
        const int q = blockIdx.x * 32 + w * 8 + i;
        const uint4* p = (const uint4*)(sims + (size_t)q * 1024 + lane * 16);
        uint4 a = p[0], b = p[1];

        unsigned k[16];
        {
            unsigned words[8] = {a.x, a.y, a.z, a.w, b.x, b.y, b.z, b.w};
            #pragma unroll
            for (int j = 0; j < 16; ++j) {
                unsigned h = (j & 1) ? (words[j >> 1] >> 16) : (words[j >> 1] & 0xFFFFu);
                unsigned m = (h ^ 0x8000u) ^ ((0u - (h >> 15)) & 0x7FFFu);
                int idx = lane * 16 + j;
                k[j] = (idx < 1000) ? ((m << 16) | (unsigned)idx) : 0u;
            }
        }
        #pragma unroll
        for (int sz = 2; sz <= 16; sz <<= 1)
            #pragma unroll
            for (int st = sz >> 1; st >= 1; st >>= 1)
                #pragma unroll
                for (int ii = 0; ii < 16; ++ii) {
                    int j = ii ^ st;
                    if (j > ii) {
                        bool desc = ((ii & sz) == 0);
                        unsigned lo = k[ii], hi = k[j];
                        unsigned mx = lo > hi ? lo : hi;
                        unsigned mn = lo > hi ? hi : lo;
                        k[ii] = desc ? mx : mn;
                        k[j] = desc ? mn : mx;
                    }
                }
        unsigned mine = 0;
        #pragma unroll
        for (int r = 0; r < 12; ++r) {
            unsigned m = k[0];
            m = dppmax<0xB1>(m);
            m = dppmax<0x4E>(m);
            m = dppmax<0x141>(m);
            m = dppmax<0x140>(m);
            m = dppmax<0x142>(m);
            m = dppmax<0x143>(m);
            unsigned wm = (unsigned)__builtin_amdgcn_readlane((int)m, 63);
            if (lane == r) mine = wm;
            if (k[0] == wm) {
                #pragma unroll
                for (int s = 0; s < 12; ++s) k[s] = k[s + 1];
            }
        }
        if (lane < 12) top[(size_t)(qoff + q) * NC + lane] = (int)(mine & 0xFFFFu);
    }
}

// -------------------------------------------------------------- refine ------
// Also emits featbf (bf16 copy of feat) so k_mlp can consume A-fragments
// straight from global with no LDS staging / no per-chunk barriers.
__global__ __launch_bounds__(256) void k_refine(const float* __restrict__ feat,
        const float* __restrict__ bank, const int* __restrict__ top,
        const double* __restrict__ binv, short* __restrict__ nf,
        short* __restrict__ featbf)
{
    __shared__ int    cidxL[16 * NC];
    __shared__ float  bdF[16 * NC];
    __shared__ double bdD[16 * NC];
    __shared__ float  simsF[16 * NC];
    __shared__ double simsD[16 * NC];
    __shared__ float  qiL[16];
    __shared__ int    flagL[16];
    __shared__ int    selidx[16][5];
    __shared__ float  selw[16][5];

    const int t = threadIdx.x, lane = t & 63, w = t >> 6;
    const int g = lane >> 4, u = lane & 15;
    const int ql = w * 4 + g;
    const int qbase = blockIdx.x * 16;
    const int q = qbase + ql;

    if (t < 16 * NC) {
        const int c = top[(size_t)qbase * NC + t];
        cidxL[t] = c;
        const double b = binv[c];
        bdD[t] = b; bdF[t] = (float)b;
    }
    __syncthreads();

    int ci[NC];
    #pragma unroll
    for (int c = 0; c < NC; ++c) ci[c] = cidxL[ql * NC + c];

    float qf[16];
    float ssf = 0.f;
    #pragma unroll
    for (int j = 0; j < 4; ++j) {
        float4 v = *(const float4*)(feat + (size_t)q * DIM + j * 64 + u * 4);
        qf[j*4+0] = v.x; qf[j*4+1] = v.y; qf[j*4+2] = v.z; qf[j*4+3] = v.w;
        ssf += v.x*v.x + v.y*v.y + v.z*v.z + v.w*v.w;
    }
    // emit bf16 feat copy (same f32bf rounding k_mlp used to apply inline)
    {
        short* fb = featbf + (size_t)q * DIM + u * 4;
        #pragma unroll
        for (int j = 0; j < 4; ++j) {
            uint2 pk;
            pk.x = ((unsigned)(unsigned short)f32bf(qf[j*4+0])) |
                   (((unsigned)(unsigned short)f32bf(qf[j*4+1])) << 16);
            pk.y = ((unsigned)(unsigned short)f32bf(qf[j*4+2])) |
                   (((unsigned)(unsigned short)f32bf(qf[j*4+3])) << 16);
            *(uint2*)(fb + j * 64) = pk;
        }
    }
    #pragma unroll
    for (int o = 1; o < 16; o <<= 1) ssf += __shfl_xor(ssf, o, 16);
    float nq = sqrtf(ssf); if (nq < 1e-12f) nq = 1e-12f;
    if (u == 0) qiL[ql] = 1.f / nq;

    float s[NC];
    #pragma unroll
    for (int c = 0; c < NC; ++c) {
        const float* brow = bank + (size_t)ci[c] * DIM + u * 4;
        float a0 = 0.f, a1 = 0.f, a2 = 0.f, a3 = 0.f;
        #pragma unroll
        for (int j = 0; j < 4; ++j) {
            float4 b = *(const float4*)(brow + j * 64);
            a0 += qf[j*4+0] * b.x; a1 += qf[j*4+1] * b.y;
            a2 += qf[j*4+2] * b.z; a3 += qf[j*4+3] * b.w;
        }
        s[c] = (a0 + a1) + (a2 + a3);
    }
    #pragma unroll
    for (int o = 1; o < 16; o <<= 1)
        #pragma unroll
        for (int c = 0; c < NC; ++c) s[c] += __shfl_xor(s[c], o, 16);
    #pragma unroll
    for (int c = 0; c < NC; ++c) if (u == c) simsF[ql * NC + c] = s[c];
    __syncthreads();

    if (t < 16) {
        const float qi2 = qiL[t];
        float vf[NC];
        unsigned long long key[NC];
        int cid[NC];
        #pragma unroll
        for (int c = 0; c < NC; ++c) {
            cid[c] = cidxL[t * NC + c];
            float v = simsF[t * NC + c] * qi2 * bdF[t * NC + c];
            vf[c] = v;
            unsigned ub = __builtin_bit_cast(unsigned, v);
            unsigned m = (ub >> 31) ? ~ub : (ub | 0x80000000u);
            key[c] = ((unsigned long long)m << 10) | (unsigned long long)(1023 - cid[c]);
        }
        int rank[NC];
        #pragma unroll
        for (int c = 0; c < NC; ++c) rank[c] = 0;
        #pragma unroll
        for (int c1 = 0; c1 < NC; ++c1)
            #pragma unroll
            for (int c2 = c1 + 1; c2 < NC; ++c2) {
                const bool gt = key[c1] > key[c2];
                rank[c2] += gt ? 1 : 0;
                rank[c1] += gt ? 0 : 1;
            }
        float v5 = 0.f, v6 = 0.f;
        #pragma unroll
        for (int c = 0; c < NC; ++c) {
            v5 += (rank[c] == 4) ? vf[c] : 0.f;
            v6 += (rank[c] == 5) ? vf[c] : 0.f;
        }
        flagL[t] = (v5 - v6) < 2e-6f;

        float vm = vf[0];
        #pragma unroll
        for (int c = 1; c < NC; ++c) vm = fmaxf(vm, vf[c]);
        float e[NC]; float wsum = 0.f;
        #pragma unroll
        for (int c = 0; c < NC; ++c) {
            float ex = __expf(vf[c] - vm);
            ex = (rank[c] < 5) ? ex : 0.f;
            e[c] = ex; wsum += ex;
        }
        const float inv = 1.f / wsum;
        #pragma unroll
        for (int k = 0; k < 5; ++k) {
            int idx = 0; float wv = 0.f;
            #pragma unroll
            for (int c = 0; c < NC; ++c) {
                const bool is = (rank[c] == k);
                idx += is ? cid[c] : 0;
                wv  += is ? e[c]  : 0.f;
            }
            selidx[t][k] = idx; selw[t][k] = wv * inv;
        }
    }
    __syncthreads();

    if (flagL[ql]) {
        double ssd = 0.0;
        #pragma unroll
        for (int j = 0; j < 16; ++j) ssd += (double)qf[j] * (double)qf[j];
        #pragma unroll
        for (int o = 1; o < 16; o <<= 1) ssd += __shfl_xor(ssd, o, 16);
        double nd = sqrt(ssd); if (nd < 1e-12) nd = 1e-12;
        const double qid = 1.0 / nd;
        double sd[NC];
        #pragma unroll
        for (int c = 0; c < NC; ++c) {
            const float* brow = bank + (size_t)ci[c] * DIM + u * 4;
            double a0 = 0, a1 = 0, a2 = 0, a3 = 0;
            #pragma unroll
            for (int j = 0; j < 4; ++j) {
                float4 b = *(const float4*)(brow + j * 64);
                a0 += (double)qf[j*4+0] * b.x; a1 += (double)qf[j*4+1] * b.y;
                a2 += (double)qf[j*4+2] * b.z; a3 += (double)qf[j*4+3] * b.w;
            }
            sd[c] = (a0 + a1) + (a2 + a3);
        }
        #pragma unroll
        for (int o = 1; o < 16; o <<= 1)
            #pragma unroll
            for (int c = 0; c < NC; ++c) sd[c] += __shfl_xor(sd[c], o, 16);
        #pragma unroll
        for (int c = 0; c < NC; ++c)
            if (u == c) simsD[ql * NC + c] = sd[c] * qid * bdD[ql * NC + c];
    }
    __syncthreads();

    if (t < 16 && flagL[t]) {
        double vd[NC];
        unsigned long long key[NC];
        int cid[NC];
        #pragma unroll
        for (int c = 0; c < NC; ++c) {
            cid[c] = cidxL[t * NC + c];
            double v = simsD[t * NC + c];
            vd[c] = v;
            unsigned long long ub = __builtin_bit_cast(unsigned long long, v);
            unsigned long long m = (ub >> 63) ? ~ub : (ub | 0x8000000000000000ULL);
            key[c] = (m & ~0x3FFULL) | (unsigned long long)(1023 - cid[c]);
        }
        int rank[NC];
        #pragma unroll
        for (int c = 0; c < NC; ++c) rank[c] = 0;
        #pragma unroll
        for (int c1 = 0; c1 < NC; ++c1)
            #pragma unroll
            for (int c2 = c1 + 1; c2 < NC; ++c2) {
                const bool gt = key[c1] > key[c2];
                rank[c2] += gt ? 1 : 0;
                rank[c1] += gt ? 0 : 1;
            }
        float vf[NC];
        #pragma unroll
        for (int c = 0; c < NC; ++c) vf[c] = (float)vd[c];
        float vm = vf[0];
        #pragma unroll
        for (int c = 1; c < NC; ++c) vm = fmaxf(vm, vf[c]);
        float e[NC]; float wsum = 0.f;
        #pragma unroll
        for (int c = 0; c < NC; ++c) {
            float ex = __expf(vf[c] - vm);
            ex = (rank[c] < 5) ? ex : 0.f;
            e[c] = ex; wsum += ex;
        }
        const float inv = 1.f / wsum;
        #pragma unroll
        for (int k = 0; k < 5; ++k) {
            int idx = 0; float wv = 0.f;
            #pragma unroll
            for (int c = 0; c < NC; ++c) {
                const bool is = (rank[c] == k);
                idx += is ? cid[c] : 0;
                wv  += is ? e[c]  : 0.f;
            }
            selidx[t][k] = idx; selw[t][k] = wv * inv;
        }
    }
    __syncthreads();

    float wk[5]; int ik[5];
    #pragma unroll
    for (int k = 0; k < 5; ++k) { wk[k] = selw[ql][k]; ik[k] = selidx[ql][k]; }
    float4 oa[4];
    #pragma unroll
    for (int j = 0; j < 4; ++j) { oa[j].x = 0.f; oa[j].y = 0.f; oa[j].z = 0.f; oa[j].w = 0.f; }
    #pragma unroll
    for (int k = 0; k < 5; ++k) {
        const float wc = wk[k];
        const float* brow = bank + (size_t)ik[k] * DIM + u * 4;
        #pragma unroll
        for (int j = 0; j < 4; ++j) {
            float4 b = *(const float4*)(brow + j * 64);
            oa[j].x += wc * b.x; oa[j].y += wc * b.y;
            oa[j].z += wc * b.z; oa[j].w += wc * b.w;
        }
    }
    short* od = nf + (size_t)q * DIM + u * 4;
    #pragma unroll
    for (int j = 0; j < 4; ++j) {
        uint2 pk;
        pk.x = ((unsigned)(unsigned short)f32bf(oa[j].x)) |
               (((unsigned)(unsigned short)f32bf(oa[j].y)) << 16);
        pk.y = ((unsigned)(unsigned short)f32bf(oa[j].z)) |
               (((unsigned)(unsigned short)f32bf(oa[j].w)) << 16);
        *(uint2*)(od + j * 64) = pk;
    }
}

// ---------------------------------------------------------- fused MLP v3 ----
// (reverted from v4: the 32-row tile's launch_bounds(256,6) capped VGPR at
// 40 and destroyed per-wave load ILP -> 128us. v3's 64 VGPR + 64 AGPR at
// 4 blocks/CU measured 86us. ILP > TLP here.)
__global__ __launch_bounds__(256, 4) void k_mlp(const short* __restrict__ featbf,
        const short* __restrict__ nf, const short* __restrict__ w1bf,
        const short* __restrict__ w2bf, const float* __restrict__ b1,
        const float* __restrict__ b2, float* __restrict__ out)
{
    __shared__ alignas(16) short Hs[64 * 264];
    const int t = threadIdx.x, lane = t & 63, w = t >> 6;
    const int mb = blockIdx.x * 64;
    const int n16 = lane & 15, ko = (lane >> 4) << 3;
    const int rq = (lane >> 4) << 2, cc = lane & 15;
    const f32x4 vzero = {0.f, 0.f, 0.f, 0.f};

    f32x4 acc[4][4];
    #pragma unroll
    for (int a = 0; a < 4; ++a)
        #pragma unroll
        for (int b = 0; b < 4; ++b) acc[a][b] = vzero;

    const short* A0 = featbf + (size_t)mb * 256 + ko;
    const short* A1 = nf     + (size_t)mb * 256 + ko;
    const short* Wp = w1bf + (size_t)(w * 64 + n16) * 512 + ko;

    // ---- layer 1, K-chunks 0..7: A = featbf ----
    #pragma unroll
    for (int kc = 0; kc < 8; ++kc) {
        short8 af[4], bf[4];
        #pragma unroll
        for (int mt = 0; mt < 4; ++mt)
            af[mt] = *(const short8*)(A0 + (mt * 16 + n16) * 256 + kc * 32);
        #pragma unroll
        for (int nt = 0; nt < 4; ++nt)
            bf[nt] = *(const short8*)(Wp + (size_t)nt * 16 * 512 + kc * 32);
        #pragma unroll
        for (int mt = 0; mt < 4; ++mt)
            #pragma unroll
            for (int nt = 0; nt < 4; ++nt)
                acc[mt][nt] = __builtin_amdgcn_mfma_f32_16x16x32_bf16(af[mt], bf[nt], acc[mt][nt], 0, 0, 0);
    }
    // ---- layer 1, K-chunks 8..15: A = nf ----
    #pragma unroll
    for (int kc = 0; kc < 8; ++kc) {
        short8 af[4], bf[4];
        #pragma unroll
        for (int mt = 0; mt < 4; ++mt)
            af[mt] = *(const short8*)(A1 + (mt * 16 + n16) * 256 + kc * 32);
        #pragma unroll
        for (int nt = 0; nt < 4; ++nt)
            bf[nt] = *(const short8*)(Wp + (size_t)nt * 16 * 512 + (kc + 8) * 32);
        #pragma unroll
        for (int mt = 0; mt < 4; ++mt)
            #pragma unroll
            for (int nt = 0; nt < 4; ++nt)
                acc[mt][nt] = __builtin_amdgcn_mfma_f32_16x16x32_bf16(af[mt], bf[nt], acc[mt][nt], 0, 0, 0);
    }

    // epilogue 1: bias + relu -> Hs
    #pragma unroll
    for (int mt = 0; mt < 4; ++mt)
        #pragma unroll
        for (int nt = 0; nt < 4; ++nt) {
            const int row = mt * 16 + rq;
            const int col = w * 64 + nt * 16 + cc;
            const float bias = b1[col];
            #pragma unroll
            for (int rr = 0; rr < 4; ++rr) {
                float v = acc[mt][nt][rr] + bias;
                Hs[(row + rr) * 264 + col] = f32bf(fmaxf(v, 0.f));
            }
        }
    #pragma unroll
    for (int a = 0; a < 4; ++a)
        #pragma unroll
        for (int b = 0; b < 4; ++b) acc[a][b] = vzero;
    __syncthreads();

    // ---- layer 2: barrier-free K-loop (Hs read-only, weights global) ----
    #pragma unroll
    for (int kc = 0; kc < 8; ++kc) {
        short8 bf[4];
        #pragma unroll
        for (int nt = 0; nt < 4; ++nt)
            bf[nt] = *(const short8*)(w2bf + (size_t)(w * 64 + nt * 16 + n16) * 256 + kc * 32 + ko);
        short8 af[4];
        #pragma unroll
        for (int mt = 0; mt < 4; ++mt)
            af[mt] = *(const short8*)(Hs + (mt * 16 + n16) * 264 + kc * 32 + ko);
        #pragma unroll
        for (int mt = 0; mt < 4; ++mt)
            #pragma unroll
            for (int nt = 0; nt < 4; ++nt)
                acc[mt][nt] = __builtin_amdgcn_mfma_f32_16x16x32_bf16(af[mt], bf[nt], acc[mt][nt], 0, 0, 0);
    }
    #pragma unroll
    for (int mt = 0; mt < 4; ++mt)
        #pragma unroll
        for (int nt = 0; nt < 4; ++nt) {
            const int row = mb + mt * 16 + rq;
            const int col = w * 64 + nt * 16 + cc;
            const float bias = b2[col];
            #pragma unroll
            for (int rr = 0; rr < 4; ++rr)
                out[(size_t)(row + rr) * 256 + col] = acc[mt][nt][rr] + bias;
        }
}

// ------------------------------------------------------------- launcher -----
extern "C" void kernel_launch(void* const* d_in, const int* in_sizes, int n_in,
                              void* d_out, int out_size, void* d_ws, size_t ws_size,
                              hipStream_t stream) {
    const float* feat = (const float*)d_in[0];
    const float* bank = (const float*)d_in[1];
    const float* W1   = (const float*)d_in[2];
    const float* b1   = (const float*)d_in[3];
    const float* W2   = (const float*)d_in[4];
    const float* b2   = (const float*)d_in[5];
    float* out = (float*)d_out;

    char* ws = (char*)d_ws;
    short*  bnbf = (short*)(ws + 0);              // 1024*256*2   = 524288
    double* binv = (double*)(ws + 524288);        // 1024*8       = 8192
    short*  w1bf = (short*)(ws + 532480);         // 131072*2     = 262144
    short*  w2bf = (short*)(ws + 794624);         // 65536*2      = 131072
    int*    top  = (int*)(ws + 925696);           // 65536*12*4   = 3145728
    short*  nf   = (short*)(ws + 4071424);        // 65536*256*2  = 33554432
    short*  X    = (short*)(ws + 37625856);       // 33554432: sims slices
    // featbf ALIASES X: the sims slice loop is fully done before k_refine
    // runs, so the 33.5 MB slice buffer is dead by then.
    short*  featbf = X;                           // 65536*256*2  = 33554432
    // total 71180288 bytes

    k_prep<<<1792, 256, 0, stream>>>(bank, W1, W2, bnbf, binv, w1bf, w2bf);
    for (int s = 0; s < 4; ++s)
        k_sims<<<512, 256, 0, stream>>>(feat, bnbf, X, top, s * 16384);
    k_refine<<<4096, 256, 0, stream>>>(feat, bank, top, binv, nf, featbf);
    k_mlp  <<<1024, 256, 0, stream>>>(featbf, nf, w1bf, w2bf, b1, b2, out);
}